// Round 1
// baseline (248.113 us; speedup 1.0000x reference)
//
#include <hip/hip_runtime.h>
#include <math.h>

// Problem constants (fixed by the reference):
//   N = B*C = 65536 rows, D=256, H=128, OSH=32
// Analytic collapse of the reference:
//   t = tanh(W1 @ x_n); v = tanh(W2 @ t); z = Wout . v
//   a = sum_h sob[h] * sin(2*pi*soa[h]*z/7)      (g is odd, g(0)=0)
//   out = sign(a) * 4*z*e^{|a|} / (4*e^{|a|} + 5),   0 if a == 0
// (intermediate scorers are dead code: no pruning happens at layers 1/2 and
//  their scores are overwritten before use)

#define NROWS 65536
#define BM 32

__global__ __launch_bounds__(256, 2)
void fused_mlp_kernel(const float* __restrict__ x,
                      const float* __restrict__ W1,
                      const float* __restrict__ W2,
                      const float* __restrict__ Wout,
                      const float* __restrict__ soa,
                      const float* __restrict__ sob,
                      float* __restrict__ out)
{
    // 64 KiB static LDS, float4 granular, XOR-swizzled layouts
    __shared__ float4 smem[4096];
    float4* const xs = smem;          // [32][64]  x tile (swz: fc ^ (r>>2 & 7))
    float4* const ws = smem + 2048;   // [128][8]  weight chunk (swz: fc ^ (o>>2 & 7))
    float4* const ts = smem + 3072;   // [32][32]  T tile (swz: fc ^ (r>>2 & 7))
    float4* const vs = smem;          // alias xs: V tile [32][32]

    const int tid  = threadIdx.x;
    const int wv_  = tid >> 6;        // wave id 0..3
    const int lane = tid & 63;
    const int rr   = lane & 7;        // row group: rows rr*4 .. rr*4+3
    const int oo   = lane >> 3;       // 0..7
    const int obase = wv_ * 32 + oo * 4;

    const int n0 = blockIdx.x * BM;

    // ---- stage x tile: 32 rows x 256 floats = 2048 float4, coalesced ----
    const float4* xg = reinterpret_cast<const float4*>(x) + (size_t)n0 * 64;
    #pragma unroll
    for (int i = 0; i < 8; ++i) {
        int flat = tid + i * 256;
        int r = flat >> 6, fc = flat & 63;
        xs[r * 64 + (fc ^ ((r >> 2) & 7))] = xg[flat];
    }

    float acc[4][4];
    #pragma unroll
    for (int i = 0; i < 4; ++i)
        #pragma unroll
        for (int j = 0; j < 4; ++j) acc[i][j] = 0.f;

    // ---- layer 1: acc[r][o] = sum_f x[r][f] * W1[o][f], K=256, 8 chunks ----
    const float4* w1g = reinterpret_cast<const float4*>(W1);  // [128][64]
    for (int kc = 0; kc < 8; ++kc) {
        __syncthreads();
        #pragma unroll
        for (int i = 0; i < 4; ++i) {
            int flat = tid + i * 256;
            int o = flat >> 3, fc = flat & 7;
            ws[o * 8 + (fc ^ ((o >> 2) & 7))] = w1g[o * 64 + kc * 8 + fc];
        }
        __syncthreads();
        #pragma unroll
        for (int fc = 0; fc < 8; ++fc) {
            float4 xv[4], wvv[4];
            #pragma unroll
            for (int i = 0; i < 4; ++i)
                xv[i] = xs[(rr * 4 + i) * 64 + ((kc * 8 + fc) ^ rr)];
            #pragma unroll
            for (int j = 0; j < 4; ++j)
                wvv[j] = ws[(obase + j) * 8 + (fc ^ oo)];
            #pragma unroll
            for (int i = 0; i < 4; ++i)
                #pragma unroll
                for (int j = 0; j < 4; ++j)
                    acc[i][j] += xv[i].x * wvv[j].x + xv[i].y * wvv[j].y
                               + xv[i].z * wvv[j].z + xv[i].w * wvv[j].w;
        }
    }

    // ---- epilogue 1: T = tanh(acc) -> ts ----
    #pragma unroll
    for (int i = 0; i < 4; ++i) {
        int r = rr * 4 + i;
        float4 tv;
        tv.x = tanhf(acc[i][0]);
        tv.y = tanhf(acc[i][1]);
        tv.z = tanhf(acc[i][2]);
        tv.w = tanhf(acc[i][3]);
        ts[r * 32 + ((wv_ * 8 + oo) ^ rr)] = tv;
        acc[i][0] = acc[i][1] = acc[i][2] = acc[i][3] = 0.f;
    }

    // ---- layer 2: K=128, 4 chunks ----
    const float4* w2g = reinterpret_cast<const float4*>(W2);  // [128][32]
    for (int kc = 0; kc < 4; ++kc) {
        __syncthreads();
        #pragma unroll
        for (int i = 0; i < 4; ++i) {
            int flat = tid + i * 256;
            int o = flat >> 3, fc = flat & 7;
            ws[o * 8 + (fc ^ ((o >> 2) & 7))] = w2g[o * 32 + kc * 8 + fc];
        }
        __syncthreads();
        #pragma unroll
        for (int fc = 0; fc < 8; ++fc) {
            float4 xv[4], wvv[4];
            #pragma unroll
            for (int i = 0; i < 4; ++i)
                xv[i] = ts[(rr * 4 + i) * 32 + ((kc * 8 + fc) ^ rr)];
            #pragma unroll
            for (int j = 0; j < 4; ++j)
                wvv[j] = ws[(obase + j) * 8 + (fc ^ oo)];
            #pragma unroll
            for (int i = 0; i < 4; ++i)
                #pragma unroll
                for (int j = 0; j < 4; ++j)
                    acc[i][j] += xv[i].x * wvv[j].x + xv[i].y * wvv[j].y
                               + xv[i].z * wvv[j].z + xv[i].w * wvv[j].w;
        }
    }

    // ---- epilogue 2: V = tanh(acc) -> vs (aliases xs; xs is dead) ----
    #pragma unroll
    for (int i = 0; i < 4; ++i) {
        int r = rr * 4 + i;
        float4 tv;
        tv.x = tanhf(acc[i][0]);
        tv.y = tanhf(acc[i][1]);
        tv.z = tanhf(acc[i][2]);
        tv.w = tanhf(acc[i][3]);
        vs[r * 32 + ((wv_ * 8 + oo) ^ rr)] = tv;
    }
    __syncthreads();

    // ---- phase C: z = V . Wout, then analytic path-collapse ----
    {
        const int r   = tid >> 3;   // 0..31
        const int sub = tid & 7;    // 8 threads per row
        const float4* wog = reinterpret_cast<const float4*>(Wout);  // 32 float4
        float z = 0.f;
        #pragma unroll
        for (int s = 0; s < 4; ++s) {
            int fc2 = sub + 8 * s;
            float4 vvv = vs[r * 32 + (fc2 ^ ((r >> 2) & 7))];
            float4 wo  = wog[fc2];
            z += vvv.x * wo.x + vvv.y * wo.y + vvv.z * wo.z + vvv.w * wo.w;
        }
        z += __shfl_xor(z, 1, 8);
        z += __shfl_xor(z, 2, 8);
        z += __shfl_xor(z, 4, 8);

        if (sub == 0) {
            const float CC = 0.8975979010256552f;  // 2*pi/7
            float a = 0.f;
            #pragma unroll 8
            for (int h = 0; h < 32; ++h)
                a += sob[h] * sinf(CC * soa[h] * z);
            float m   = expf(fabsf(a));
            float res = 4.f * z * m / (4.f * m + 5.f);
            out[n0 + r] = (a > 0.f) ? res : ((a < 0.f) ? -res : 0.f);
        }
    }
}

extern "C" void kernel_launch(void* const* d_in, const int* in_sizes, int n_in,
                              void* d_out, int out_size, void* d_ws, size_t ws_size,
                              hipStream_t stream) {
    const float* x    = (const float*)d_in[0];
    const float* W1   = (const float*)d_in[1];
    const float* W2   = (const float*)d_in[2];
    const float* Wout = (const float*)d_in[3];
    const float* soa  = (const float*)d_in[8];
    const float* sob  = (const float*)d_in[9];
    float* outp = (float*)d_out;

    dim3 grid(NROWS / BM);   // 2048
    dim3 block(256);
    hipLaunchKernelGGL(fused_mlp_kernel, grid, block, 0, stream,
                       x, W1, W2, Wout, soa, sob, outp);
}